// Round 1
// baseline (747.098 us; speedup 1.0000x reference)
//
#include <hip/hip_runtime.h>

typedef __attribute__((ext_vector_type(4))) float f32x4;
typedef __attribute__((ext_vector_type(8))) __bf16 bf16x8;
typedef __attribute__((ext_vector_type(8))) unsigned short ushort8;
typedef __attribute__((ext_vector_type(4))) unsigned short ushort4v;

#define EMBED 1024
#define SEQ   2048
#define BATCH 4
#define HEADS 16
#define HDIM  64
// log2(e) / sqrt(EMBED) : combines the 1/32 scale with exp->exp2
#define SCL 0.045084220027780106f

static __device__ __forceinline__ unsigned short f2bf(float f) {
  unsigned u = __builtin_bit_cast(unsigned, f);
  u += 0x7FFFu + ((u >> 16) & 1u);   // RNE
  return (unsigned short)(u >> 16);
}
static __device__ __forceinline__ bf16x8 ldg8(const unsigned short* p) {
  return __builtin_bit_cast(bf16x8, *(const ushort8*)p);
}

// ---- pack int32 mask -> bitmask (bit k of word w = mask[w*64+k] != 0) ----
__global__ __launch_bounds__(256) void pack_mask_kernel(
    const int* __restrict__ m, unsigned long long* __restrict__ out) {
  int t = blockIdx.x * 256 + threadIdx.x;
  unsigned long long bits = __ballot(m[t] != 0);
  if ((threadIdx.x & 63) == 0) out[t >> 6] = bits;
}

// ---- C[M x 1024] = X[M x 1024] @ W^T + bias ----
// OUT_MODE 0: bf16 row-major   1: bf16 vpT[b][h][d][s]   2: f32 row-major
template<int OUT_MODE>
__global__ __launch_bounds__(256) void gemm_xwt(
    const float* __restrict__ X, const float* __restrict__ W,
    const float* __restrict__ bias, void* __restrict__ outp) {
  __shared__ unsigned short Abuf[2][128 * 40];
  __shared__ unsigned short Bbuf[2][128 * 40];
  const int tid = threadIdx.x, lane = tid & 63, wv = tid >> 6;
  const int wy = wv >> 1, wx = wv & 1, ln = lane & 15, g = lane >> 4;
  const int mbase = blockIdx.y * 128, nbase = blockIdx.x * 128;
  const int sr = tid >> 3;         // 0..31
  const int sc = (tid & 7) * 4;    // 0..28
  const float* Xp = X + (size_t)(mbase + sr) * EMBED + sc;
  const float* Wp = W + (size_t)(nbase + sr) * EMBED + sc;

  f32x4 ar[4], br[4];
  f32x4 acc[4][4];
#pragma unroll
  for (int i = 0; i < 4; i++)
#pragma unroll
    for (int j = 0; j < 4; j++) acc[i][j] = (f32x4){0.f, 0.f, 0.f, 0.f};

  auto LOADG = [&](int kt) {
#pragma unroll
    for (int p = 0; p < 4; p++) {
      ar[p] = *(const f32x4*)(Xp + (size_t)p * 32 * EMBED + kt * 32);
      br[p] = *(const f32x4*)(Wp + (size_t)p * 32 * EMBED + kt * 32);
    }
  };
  auto WRITES = [&](int buf) {
#pragma unroll
    for (int p = 0; p < 4; p++) {
      ushort4v a4, b4;
#pragma unroll
      for (int i = 0; i < 4; i++) { a4[i] = f2bf(ar[p][i]); b4[i] = f2bf(br[p][i]); }
      *(ushort4v*)&Abuf[buf][(sr + p * 32) * 40 + sc] = a4;
      *(ushort4v*)&Bbuf[buf][(sr + p * 32) * 40 + sc] = b4;
    }
  };

  LOADG(0);
  WRITES(0);
  const int NT = EMBED / 32;
  for (int kt = 0; kt < NT; ++kt) {
    __syncthreads();
    const int cur = kt & 1;
    if (kt + 1 < NT) LOADG(kt + 1);
    bf16x8 af[4], bfr[4];
#pragma unroll
    for (int ms = 0; ms < 4; ++ms)
      af[ms] = __builtin_bit_cast(bf16x8,
          *(const ushort8*)&Abuf[cur][(wy * 64 + ms * 16 + ln) * 40 + g * 8]);
#pragma unroll
    for (int ns = 0; ns < 4; ++ns)
      bfr[ns] = __builtin_bit_cast(bf16x8,
          *(const ushort8*)&Bbuf[cur][(wx * 64 + ns * 16 + ln) * 40 + g * 8]);
#pragma unroll
    for (int ms = 0; ms < 4; ++ms)
#pragma unroll
      for (int ns = 0; ns < 4; ++ns)
        acc[ms][ns] = __builtin_amdgcn_mfma_f32_16x16x32_bf16(
            af[ms], bfr[ns], acc[ms][ns], 0, 0, 0);
    if (kt + 1 < NT) WRITES((kt + 1) & 1);
  }

  float bv[4];
#pragma unroll
  for (int ns = 0; ns < 4; ++ns) bv[ns] = bias[nbase + wx * 64 + ns * 16 + ln];

  if (OUT_MODE == 0) {
    unsigned short* out = (unsigned short*)outp;
#pragma unroll
    for (int ms = 0; ms < 4; ++ms)
#pragma unroll
      for (int ns = 0; ns < 4; ++ns) {
        int col = nbase + wx * 64 + ns * 16 + ln;
#pragma unroll
        for (int j = 0; j < 4; ++j) {
          int row = mbase + wy * 64 + ms * 16 + g * 4 + j;
          out[(size_t)row * EMBED + col] = f2bf(acc[ms][ns][j] + bv[ns]);
        }
      }
  } else if (OUT_MODE == 1) {
    unsigned short* out = (unsigned short*)outp;
#pragma unroll
    for (int ms = 0; ms < 4; ++ms)
#pragma unroll
      for (int ns = 0; ns < 4; ++ns) {
        int row0 = mbase + wy * 64 + ms * 16 + g * 4;
        int col = nbase + wx * 64 + ns * 16 + ln;
        int b = row0 >> 11, s0 = row0 & (SEQ - 1);
        int h = col >> 6, d = col & 63;
        ushort4v pk;
#pragma unroll
        for (int j = 0; j < 4; ++j) pk[j] = f2bf(acc[ms][ns][j] + bv[ns]);
        *(ushort4v*)&out[(size_t)((b * HEADS + h) * HDIM + d) * SEQ + s0] = pk;
      }
  } else {
    float* out = (float*)outp;
#pragma unroll
    for (int ms = 0; ms < 4; ++ms)
#pragma unroll
      for (int ns = 0; ns < 4; ++ns) {
        int col = nbase + wx * 64 + ns * 16 + ln;
#pragma unroll
        for (int j = 0; j < 4; ++j) {
          int row = mbase + wy * 64 + ms * 16 + g * 4 + j;
          out[(size_t)row * EMBED + col] = acc[ms][ns][j] + bv[ns];
        }
      }
  }
}

// ---- attention: per block (b, h, 64 q-rows), per wave 16 q-rows ----
__global__ __launch_bounds__(256) void attn_kernel(
    const unsigned short* __restrict__ qp, const unsigned short* __restrict__ kp,
    const unsigned short* __restrict__ vpT,
    const unsigned long long* __restrict__ mask64, float* __restrict__ att) {
  __shared__ unsigned short Plds[4][16 * 72];
  const int tid = threadIdx.x, lane = tid & 63, wv = tid >> 6;
  const int ln = lane & 15, g = lane >> 4;
  const int b = blockIdx.z, h = blockIdx.y;
  const int qbase = blockIdx.x * 64 + wv * 16;
  const int qrow = b * SEQ + qbase + ln;

  // Q stays in registers (B-operand of transposed QK^T)
  bf16x8 qf0 = ldg8(qp + (size_t)qrow * EMBED + h * HDIM + g * 8);
  bf16x8 qf1 = ldg8(qp + (size_t)qrow * EMBED + h * HDIM + 32 + g * 8);

  f32x4 oacc[4];
#pragma unroll
  for (int ds = 0; ds < 4; ++ds) oacc[ds] = (f32x4){0.f, 0.f, 0.f, 0.f};
  float den = 0.f;

  const unsigned short* kbp = kp + (size_t)b * SEQ * EMBED + h * HDIM;
  const unsigned short* vbp = vpT + (size_t)((b * HEADS + h) * HDIM) * SEQ;
  const unsigned long long* mrow = mask64 + (size_t)qrow * (SEQ / 64);
  unsigned short* pl = &Plds[wv][0];

  for (int kt = 0; kt < SEQ / 64; ++kt) {
    const int k0 = kt * 64;
    const unsigned long long mw = mrow[kt];
    // E^T = K_tile . Q^T : lane holds q=ln, k = k0 + ms*16 + g*4 + j
#pragma unroll
    for (int ms = 0; ms < 4; ++ms) {
      const unsigned short* kr = kbp + (size_t)(k0 + ms * 16 + ln) * EMBED + g * 8;
      bf16x8 a0 = ldg8(kr);
      bf16x8 a1 = ldg8(kr + 32);
      f32x4 e = (f32x4){0.f, 0.f, 0.f, 0.f};
      e = __builtin_amdgcn_mfma_f32_16x16x32_bf16(a0, qf0, e, 0, 0, 0);
      e = __builtin_amdgcn_mfma_f32_16x16x32_bf16(a1, qf1, e, 0, 0, 0);
      unsigned mb = (unsigned)(mw >> (ms * 16 + g * 4));
      ushort4v pkv;
#pragma unroll
      for (int j = 0; j < 4; ++j) {
        float p = ((mb >> j) & 1u) ? exp2f(e[j] * SCL) : 0.f;
        den += p;
        pkv[j] = f2bf(p);
      }
      *(ushort4v*)&pl[ln * 72 + ms * 16 + g * 4] = pkv;
    }
    // P roundtrip (same-wave LDS, in-order DS pipe: no barrier needed)
    bf16x8 pa0 = __builtin_bit_cast(bf16x8, *(const ushort8*)&pl[ln * 72 + g * 8]);
    bf16x8 pa1 = __builtin_bit_cast(bf16x8, *(const ushort8*)&pl[ln * 72 + 32 + g * 8]);
#pragma unroll
    for (int ds = 0; ds < 4; ++ds) {
      const unsigned short* vr = vbp + (size_t)(ds * 16 + ln) * SEQ + k0 + g * 8;
      bf16x8 v0 = ldg8(vr);
      bf16x8 v1 = ldg8(vr + 32);
      oacc[ds] = __builtin_amdgcn_mfma_f32_16x16x32_bf16(pa0, v0, oacc[ds], 0, 0, 0);
      oacc[ds] = __builtin_amdgcn_mfma_f32_16x16x32_bf16(pa1, v1, oacc[ds], 0, 0, 0);
    }
  }
  // denominator: lanes {ln, ln+16, ln+32, ln+48} hold partials for q=ln
  den += __shfl_xor(den, 16);
  den += __shfl_xor(den, 32);
  float dinv[4];
#pragma unroll
  for (int j = 0; j < 4; ++j) dinv[j] = 1.0f / __shfl(den, g * 4 + j);
#pragma unroll
  for (int ds = 0; ds < 4; ++ds)
#pragma unroll
    for (int j = 0; j < 4; ++j)
      att[(size_t)(b * SEQ + qbase + g * 4 + j) * EMBED + h * HDIM + ds * 16 + ln] =
          oacc[ds][j] * dinv[j];
}

extern "C" void kernel_launch(void* const* d_in, const int* in_sizes, int n_in,
                              void* d_out, int out_size, void* d_ws, size_t ws_size,
                              hipStream_t stream) {
  const float* q    = (const float*)d_in[0];
  const float* k    = (const float*)d_in[1];
  const float* v    = (const float*)d_in[2];
  const int*   mask = (const int*)d_in[3];
  const float* wq_w = (const float*)d_in[4];
  const float* wq_b = (const float*)d_in[5];
  const float* wk_w = (const float*)d_in[6];
  const float* wk_b = (const float*)d_in[7];
  const float* wv_w = (const float*)d_in[8];
  const float* wv_b = (const float*)d_in[9];
  const float* fo_w = (const float*)d_in[10];
  const float* fo_b = (const float*)d_in[11];

  char* ws = (char*)d_ws;
  const size_t PROJ_BYTES = (size_t)BATCH * SEQ * EMBED * 2;  // 16 MiB
  unsigned short* qp  = (unsigned short*)(ws);
  unsigned short* kp  = (unsigned short*)(ws + PROJ_BYTES);
  unsigned short* vpT = (unsigned short*)(ws + 2 * PROJ_BYTES);
  unsigned long long* m64 = (unsigned long long*)(ws + 3 * PROJ_BYTES);
  float* attn = (float*)(ws + 3 * PROJ_BYTES + (size_t)BATCH * SEQ * SEQ / 8);

  // 1. pack mask bits (67MB -> 2MB, L3-resident for all 16 heads)
  pack_mask_kernel<<<(BATCH * SEQ * SEQ) / 256, 256, 0, stream>>>(mask, m64);

  // 2-4. projections
  dim3 gg(EMBED / 128, (BATCH * SEQ) / 128);
  gemm_xwt<0><<<gg, 256, 0, stream>>>(q, wq_w, wq_b, qp);
  gemm_xwt<0><<<gg, 256, 0, stream>>>(k, wk_w, wk_b, kp);
  gemm_xwt<1><<<gg, 256, 0, stream>>>(v, wv_w, wv_b, vpT);

  // 5. fused masked attention
  attn_kernel<<<dim3(SEQ / 64, HEADS, BATCH), 256, 0, stream>>>(qp, kp, vpT, m64, attn);

  // 6. output projection -> d_out (f32)
  gemm_xwt<2><<<gg, 256, 0, stream>>>(attn, fo_w, fo_b, (float*)d_out);
}

// Round 2
// 401.003 us; speedup vs baseline: 1.8631x; 1.8631x over previous
//
#include <hip/hip_runtime.h>

typedef __attribute__((ext_vector_type(4))) float f32x4;
typedef __attribute__((ext_vector_type(16))) float f32x16;
typedef __attribute__((ext_vector_type(8))) __bf16 bf16x8;
typedef __attribute__((ext_vector_type(8))) unsigned short ushort8;
typedef __attribute__((ext_vector_type(4))) unsigned short ushort4v;

#define EMBED 1024
#define SEQ   2048
#define BATCH 4
#define HEADS 16
#define HDIM  64
// log2(e) / sqrt(EMBED) : combines the 1/32 scale with exp->exp2
#define SCL 0.045084220027780106f

#define GLD_LDS16(g, l) __builtin_amdgcn_global_load_lds( \
    (const __attribute__((address_space(1))) void*)(g),   \
    (__attribute__((address_space(3))) void*)(l), 16, 0, 0)

static __device__ __forceinline__ unsigned short f2bf(float f) {
  unsigned u = __builtin_bit_cast(unsigned, f);
  u += 0x7FFFu + ((u >> 16) & 1u);   // RNE
  return (unsigned short)(u >> 16);
}
static __device__ __forceinline__ bf16x8 ldg8(const unsigned short* p) {
  return __builtin_bit_cast(bf16x8, *(const ushort8*)p);
}

// ---- pack int32 mask -> bitmask (bit k of word w = mask[w*64+k] != 0) ----
__global__ __launch_bounds__(256) void pack_mask_kernel(
    const int* __restrict__ m, unsigned long long* __restrict__ out) {
  int t = blockIdx.x * 256 + threadIdx.x;
  unsigned long long bits = __ballot(m[t] != 0);
  if ((threadIdx.x & 63) == 0) out[t >> 6] = bits;
}

// ---- C[M x 1024] = X[M x 1024] @ W^T + bias ----
// OUT_MODE 0: bf16 row-major   1: bf16 vpT[b][h][d][s]   2: f32 row-major
template<int OUT_MODE>
__global__ __launch_bounds__(256) void gemm_xwt(
    const float* __restrict__ X, const float* __restrict__ W,
    const float* __restrict__ bias, void* __restrict__ outp) {
  __shared__ unsigned short Abuf[2][128 * 40];
  __shared__ unsigned short Bbuf[2][128 * 40];
  const int tid = threadIdx.x, lane = tid & 63, wv = tid >> 6;
  const int wy = wv >> 1, wx = wv & 1, ln = lane & 15, g = lane >> 4;
  const int mbase = blockIdx.y * 128, nbase = blockIdx.x * 128;
  const int sr = tid >> 3;         // 0..31
  const int sc = (tid & 7) * 4;    // 0..28
  const float* Xp = X + (size_t)(mbase + sr) * EMBED + sc;
  const float* Wp = W + (size_t)(nbase + sr) * EMBED + sc;

  f32x4 ar[4], br[4];
  f32x4 acc[4][4];
#pragma unroll
  for (int i = 0; i < 4; i++)
#pragma unroll
    for (int j = 0; j < 4; j++) acc[i][j] = (f32x4){0.f, 0.f, 0.f, 0.f};

  auto LOADG = [&](int kt) {
#pragma unroll
    for (int p = 0; p < 4; p++) {
      ar[p] = *(const f32x4*)(Xp + (size_t)p * 32 * EMBED + kt * 32);
      br[p] = *(const f32x4*)(Wp + (size_t)p * 32 * EMBED + kt * 32);
    }
  };
  auto WRITES = [&](int buf) {
#pragma unroll
    for (int p = 0; p < 4; p++) {
      ushort4v a4, b4;
#pragma unroll
      for (int i = 0; i < 4; i++) { a4[i] = f2bf(ar[p][i]); b4[i] = f2bf(br[p][i]); }
      *(ushort4v*)&Abuf[buf][(sr + p * 32) * 40 + sc] = a4;
      *(ushort4v*)&Bbuf[buf][(sr + p * 32) * 40 + sc] = b4;
    }
  };

  LOADG(0);
  WRITES(0);
  const int NT = EMBED / 32;
  for (int kt = 0; kt < NT; ++kt) {
    __syncthreads();
    const int cur = kt & 1;
    if (kt + 1 < NT) LOADG(kt + 1);
    bf16x8 af[4], bfr[4];
#pragma unroll
    for (int ms = 0; ms < 4; ++ms)
      af[ms] = __builtin_bit_cast(bf16x8,
          *(const ushort8*)&Abuf[cur][(wy * 64 + ms * 16 + ln) * 40 + g * 8]);
#pragma unroll
    for (int ns = 0; ns < 4; ++ns)
      bfr[ns] = __builtin_bit_cast(bf16x8,
          *(const ushort8*)&Bbuf[cur][(wx * 64 + ns * 16 + ln) * 40 + g * 8]);
#pragma unroll
    for (int ms = 0; ms < 4; ++ms)
#pragma unroll
      for (int ns = 0; ns < 4; ++ns)
        acc[ms][ns] = __builtin_amdgcn_mfma_f32_16x16x32_bf16(
            af[ms], bfr[ns], acc[ms][ns], 0, 0, 0);
    if (kt + 1 < NT) WRITES((kt + 1) & 1);
  }

  float bv[4];
#pragma unroll
  for (int ns = 0; ns < 4; ++ns) bv[ns] = bias[nbase + wx * 64 + ns * 16 + ln];

  if (OUT_MODE == 0) {
    unsigned short* out = (unsigned short*)outp;
#pragma unroll
    for (int ms = 0; ms < 4; ++ms)
#pragma unroll
      for (int ns = 0; ns < 4; ++ns) {
        int col = nbase + wx * 64 + ns * 16 + ln;
#pragma unroll
        for (int j = 0; j < 4; ++j) {
          int row = mbase + wy * 64 + ms * 16 + g * 4 + j;
          out[(size_t)row * EMBED + col] = f2bf(acc[ms][ns][j] + bv[ns]);
        }
      }
  } else if (OUT_MODE == 1) {
    unsigned short* out = (unsigned short*)outp;
#pragma unroll
    for (int ms = 0; ms < 4; ++ms)
#pragma unroll
      for (int ns = 0; ns < 4; ++ns) {
        int row0 = mbase + wy * 64 + ms * 16 + g * 4;
        int col = nbase + wx * 64 + ns * 16 + ln;
        int b = row0 >> 11, s0 = row0 & (SEQ - 1);
        int h = col >> 6, d = col & 63;
        ushort4v pk;
#pragma unroll
        for (int j = 0; j < 4; ++j) pk[j] = f2bf(acc[ms][ns][j] + bv[ns]);
        *(ushort4v*)&out[(size_t)((b * HEADS + h) * HDIM + d) * SEQ + s0] = pk;
      }
  } else {
    float* out = (float*)outp;
#pragma unroll
    for (int ms = 0; ms < 4; ++ms)
#pragma unroll
      for (int ns = 0; ns < 4; ++ns) {
        int col = nbase + wx * 64 + ns * 16 + ln;
#pragma unroll
        for (int j = 0; j < 4; ++j) {
          int row = mbase + wy * 64 + ms * 16 + g * 4 + j;
          out[(size_t)row * EMBED + col] = acc[ms][ns][j] + bv[ns];
        }
      }
  }
}

// ---- attention v2: block = (b, h, 128 q-rows), 4 waves x 32 q-rows ----
// K/V tiles (64x64 bf16) double-buffered in LDS via global_load_lds,
// XOR-swizzled (inverse swizzle on global source, swizzle on ds_read).
__global__ __launch_bounds__(256, 3) void attn2_kernel(
    const unsigned short* __restrict__ qp, const unsigned short* __restrict__ kp,
    const unsigned short* __restrict__ vpT,
    const unsigned long long* __restrict__ mask64, float* __restrict__ att) {
  __shared__ unsigned char lds[49664];
  unsigned char* Kb = lds;               // [2][64 rows][128B]
  unsigned char* Vb = lds + 16384;       // [2][64 rows][128B]
  unsigned char* Pb = lds + 32768;       // [4 waves][32 rows][128B]
  float* denb = (float*)(lds + 49152);   // [4 waves][32]

  const int tid = threadIdx.x;
  const int lane = tid & 63, wv = tid >> 6;
  const int lo = lane & 31, hi = lane >> 5;
  const int b = blockIdx.z, h = blockIdx.y;
  const int qb = blockIdx.x * 128 + wv * 32;
  const int q = qb + lo;

  // ---- Q fragments, pre-scaled by SCL (so p = exp2(e) directly) ----
  bf16x8 qf[4];
  {
    const unsigned short* qr = qp + (size_t)(b * SEQ + q) * EMBED + h * HDIM + hi * 8;
#pragma unroll
    for (int c = 0; c < 4; ++c) {
      ushort8 u = *(const ushort8*)(qr + 16 * c);
      bf16x8 f;
#pragma unroll
      for (int j = 0; j < 8; ++j) {
        float x = __builtin_bit_cast(float, (unsigned)u[j] << 16) * SCL;
        f[j] = (__bf16)x;
      }
      qf[c] = f;
    }
  }

  // ---- staging geometry: thread covers 16B chunk; row = linear/128 ----
  const int srccol = ((lane & 7) * 16) ^ ((lane >> 3) << 4);  // inverse swizzle
  const unsigned char* kgs = (const unsigned char*)kp
      + ((size_t)(b * SEQ) * EMBED + h * HDIM) * 2 + srccol;
  const unsigned char* vgs = (const unsigned char*)vpT
      + ((size_t)(b * HEADS + h) * HDIM) * SEQ * 2 + srccol;
  const int rowA = wv * 8 + (lane >> 3);

  auto STAGE = [&](int buf, int kt) {
    const int k0 = kt * 64;
#pragma unroll
    for (int rnd = 0; rnd < 2; ++rnd) {
      const int row = rowA + rnd * 32;
      GLD_LDS16(kgs + (size_t)(k0 + row) * (EMBED * 2),
                Kb + buf * 8192 + rnd * 4096 + wv * 1024);
      GLD_LDS16(vgs + (size_t)row * (SEQ * 2) + k0 * 2,
                Vb + buf * 8192 + rnd * 4096 + wv * 1024);
    }
  };

  f32x16 oacc0, oacc1;
#pragma unroll
  for (int i = 0; i < 16; ++i) { oacc0[i] = 0.f; oacc1[i] = 0.f; }
  float den = 0.f;

  const unsigned long long* mrow = mask64 + (size_t)(b * SEQ + q) * (SEQ / 64);
  unsigned char* Pw = Pb + wv * 4096;
  const int pswz = (lo & 7) << 4;

  STAGE(0, 0);
  const int NT = SEQ / 64;
  for (int kt = 0; kt < NT; ++kt) {
    const int cur = kt & 1;
    __syncthreads();                       // drains this wave's vmcnt; joins all
    if (kt + 1 < NT) STAGE(cur ^ 1, kt + 1);
    const unsigned long long mw = mrow[kt];
    const unsigned char* Kc = Kb + cur * 8192;
    const unsigned char* Vc = Vb + cur * 8192;

    // ---- QK^T (swapped: A=K rows, B=Q rows -> D[k][q], col=lane&31=q) ----
#pragma unroll
    for (int kg = 0; kg < 2; ++kg) {
      f32x16 e;
#pragma unroll
      for (int i = 0; i < 16; ++i) e[i] = 0.f;
      const int krow = kg * 32 + lo;
      const int kswz = (lo & 7) << 4;
#pragma unroll
      for (int c = 0; c < 4; ++c) {
        const int colb = (16 * c + 8 * hi) * 2;
        bf16x8 kf = *(const bf16x8*)(Kc + krow * 128 + (colb ^ kswz));
        e = __builtin_amdgcn_mfma_f32_32x32x16_bf16(kf, qf[c], e, 0, 0, 0);
      }
      // mask + exp + P write (k_local = kg*32 + 8t + 4hi + j)
      const unsigned mbits = (unsigned)(mw >> (kg * 32 + 4 * hi));
#pragma unroll
      for (int t = 0; t < 4; ++t) {
        ushort4v pk;
#pragma unroll
        for (int j = 0; j < 4; ++j) {
          float p = ((mbits >> (8 * t + j)) & 1u) ? exp2f(e[4 * t + j]) : 0.f;
          den += p;
          pk[j] = __builtin_bit_cast(unsigned short, (__bf16)p);
        }
        const int pcol = kg * 64 + 16 * t + 8 * hi;
        *(ushort4v*)(Pw + lo * 128 + (pcol ^ pswz)) = pk;
      }
    }

    // ---- PV: A=P rows (q), B=V^T rows (d) -> D[q][d], col=lane&31=d ----
#pragma unroll
    for (int c = 0; c < 4; ++c) {
      const int pcolb = 32 * c + 16 * hi;
      bf16x8 pf = *(const bf16x8*)(Pw + lo * 128 + (pcolb ^ pswz));
      {
        const int drow = lo;
        bf16x8 vf = *(const bf16x8*)(Vc + drow * 128 + (pcolb ^ ((drow & 7) << 4)));
        oacc0 = __builtin_amdgcn_mfma_f32_32x32x16_bf16(pf, vf, oacc0, 0, 0, 0);
      }
      {
        const int drow = 32 + lo;
        bf16x8 vf = *(const bf16x8*)(Vc + drow * 128 + (pcolb ^ ((drow & 7) << 4)));
        oacc1 = __builtin_amdgcn_mfma_f32_32x32x16_bf16(pf, vf, oacc1, 0, 0, 0);
      }
    }
  }

  // ---- denominator: q=lo partials live in lanes lo and lo+32 ----
  den += __shfl_xor(den, 32);
  if (hi == 0) denb[wv * 32 + lo] = den;
  // same-wave LDS write->read: DS pipe is in-order per wave
  float dinv[16];
#pragma unroll
  for (int r = 0; r < 16; ++r)
    dinv[r] = 1.0f / denb[wv * 32 + (r & 3) + 8 * (r >> 2) + 4 * hi];

  // ---- write O: lane holds d = dg*32+lo, rows q = (r&3)+8*(r>>2)+4*hi ----
#pragma unroll
  for (int r = 0; r < 16; ++r) {
    const int qq = qb + (r & 3) + 8 * (r >> 2) + 4 * hi;
    float* orow = att + (size_t)(b * SEQ + qq) * EMBED + h * HDIM;
    orow[lo] = oacc0[r] * dinv[r];
    orow[32 + lo] = oacc1[r] * dinv[r];
  }
}

extern "C" void kernel_launch(void* const* d_in, const int* in_sizes, int n_in,
                              void* d_out, int out_size, void* d_ws, size_t ws_size,
                              hipStream_t stream) {
  const float* q    = (const float*)d_in[0];
  const float* k    = (const float*)d_in[1];
  const float* v    = (const float*)d_in[2];
  const int*   mask = (const int*)d_in[3];
  const float* wq_w = (const float*)d_in[4];
  const float* wq_b = (const float*)d_in[5];
  const float* wk_w = (const float*)d_in[6];
  const float* wk_b = (const float*)d_in[7];
  const float* wv_w = (const float*)d_in[8];
  const float* wv_b = (const float*)d_in[9];
  const float* fo_w = (const float*)d_in[10];
  const float* fo_b = (const float*)d_in[11];

  char* ws = (char*)d_ws;
  const size_t PROJ_BYTES = (size_t)BATCH * SEQ * EMBED * 2;  // 16 MiB
  unsigned short* qp  = (unsigned short*)(ws);
  unsigned short* kp  = (unsigned short*)(ws + PROJ_BYTES);
  unsigned short* vpT = (unsigned short*)(ws + 2 * PROJ_BYTES);
  unsigned long long* m64 = (unsigned long long*)(ws + 3 * PROJ_BYTES);
  float* attn = (float*)(ws + 3 * PROJ_BYTES + (size_t)BATCH * SEQ * SEQ / 8);

  // 1. pack mask bits (67MB -> 2MB, L3-resident for all 16 heads)
  pack_mask_kernel<<<(BATCH * SEQ * SEQ) / 256, 256, 0, stream>>>(mask, m64);

  // 2-4. projections
  dim3 gg(EMBED / 128, (BATCH * SEQ) / 128);
  gemm_xwt<0><<<gg, 256, 0, stream>>>(q, wq_w, wq_b, qp);
  gemm_xwt<0><<<gg, 256, 0, stream>>>(k, wk_w, wk_b, kp);
  gemm_xwt<1><<<gg, 256, 0, stream>>>(v, wv_w, wv_b, vpT);

  // 5. fused masked attention
  attn2_kernel<<<dim3(SEQ / 128, HEADS, BATCH), 256, 0, stream>>>(qp, kp, vpT, m64, attn);

  // 6. output projection -> d_out (f32)
  gemm_xwt<2><<<gg, 256, 0, stream>>>(attn, fo_w, fo_b, (float*)d_out);
}

// Round 3
// 320.223 us; speedup vs baseline: 2.3331x; 1.2523x over previous
//
#include <hip/hip_runtime.h>

typedef __attribute__((ext_vector_type(4))) float f32x4;
typedef __attribute__((ext_vector_type(16))) float f32x16;
typedef __attribute__((ext_vector_type(8))) __bf16 bf16x8;
typedef __attribute__((ext_vector_type(8))) unsigned short ushort8;
typedef __attribute__((ext_vector_type(4))) unsigned short ushort4v;

#define EMBED 1024
#define SEQ   2048
#define BATCH 4
#define HEADS 16
#define HDIM  64
// log2(e) / sqrt(EMBED) : combines the 1/32 scale with exp->exp2
#define SCL 0.045084220027780106f

#define GLD_LDS16(g, l) __builtin_amdgcn_global_load_lds( \
    (const __attribute__((address_space(1))) void*)(g),   \
    (__attribute__((address_space(3))) void*)(l), 16, 0, 0)

static __device__ __forceinline__ unsigned short f2bf(float f) {
  unsigned u = __builtin_bit_cast(unsigned, f);
  u += 0x7FFFu + ((u >> 16) & 1u);   // RNE
  return (unsigned short)(u >> 16);
}

// ---- pack int32 mask -> bitmask (bit k of word w = mask[w*64+k] != 0) ----
__global__ __launch_bounds__(256) void pack_mask_kernel(
    const int* __restrict__ m, unsigned long long* __restrict__ out) {
  int t = blockIdx.x * 256 + threadIdx.x;
  unsigned long long bits = __ballot(m[t] != 0);
  if ((threadIdx.x & 63) == 0) out[t >> 6] = bits;
}

// ---- f32 -> bf16 vectorized convert (8 elems/thread) ----
__global__ __launch_bounds__(256) void cvt_kernel(
    const float* __restrict__ s, unsigned short* __restrict__ d, int nvec) {
  int i = blockIdx.x * 256 + threadIdx.x;
  if (i >= nvec) return;
  f32x4 a = ((const f32x4*)s)[2 * i];
  f32x4 b = ((const f32x4*)s)[2 * i + 1];
  ushort8 o;
#pragma unroll
  for (int j = 0; j < 4; ++j) { o[j] = f2bf(a[j]); o[4 + j] = f2bf(b[j]); }
  ((ushort8*)d)[i] = o;
}

// ---- C[M x 1024] = A[M x 1024](bf16) @ B[1024 x 1024](bf16)^T + bias ----
// m97 structure: 128x128 tile, BK=32, global_load_lds w16, 1 barrier/K-step.
// OUT_MODE 0: bf16 row-major   1: bf16 vpT[b][h][d][s]   2: f32 row-major
template<int OUT_MODE>
__global__ __launch_bounds__(256) void gemm_bt(
    const unsigned short* __restrict__ A, const unsigned short* __restrict__ B,
    const float* __restrict__ bias, void* __restrict__ outp) {
  __shared__ unsigned short Ab[2][128 * 32];
  __shared__ unsigned short Bb[2][128 * 32];
  const int tid = threadIdx.x, lane = tid & 63, wv = tid >> 6;
  const int wy = wv >> 1, wx = wv & 1, ln = lane & 15, g = lane >> 4;
  const int mbase = blockIdx.x * 128, nbase = blockIdx.y * 128;

  // staging: thread covers 16B; row = tid>>2 (+64 for round 1), bytecol=(tid&3)*16
  const int srow = tid >> 2, scol = (tid & 3) * 16;
  const char* Ag = (const char*)(A + (size_t)(mbase + srow) * EMBED) + scol;
  const char* Bg = (const char*)(B + (size_t)(nbase + srow) * EMBED) + scol;
  const size_t R64 = (size_t)64 * EMBED * 2;   // 64 rows in bytes

  f32x4 acc[4][4];
#pragma unroll
  for (int i = 0; i < 4; i++)
#pragma unroll
    for (int j = 0; j < 4; j++) acc[i][j] = (f32x4){0.f, 0.f, 0.f, 0.f};

  auto STAGE = [&](int buf, int kt) {
    const size_t koff = (size_t)kt * 64;   // BK=32 bf16 = 64 bytes
    char* al = (char*)&Ab[buf][0] + tid * 16;
    char* bl = (char*)&Bb[buf][0] + tid * 16;
    GLD_LDS16(Ag + koff, al);
    GLD_LDS16(Ag + koff + R64, al + 4096);
    GLD_LDS16(Bg + koff, bl);
    GLD_LDS16(Bg + koff + R64, bl + 4096);
  };

  STAGE(0, 0);
  const int NT = EMBED / 32;
  for (int kt = 0; kt < NT; ++kt) {
    __syncthreads();                    // waves drain vmcnt -> buf kt&1 ready
    const int cur = kt & 1;
    if (kt + 1 < NT) STAGE(cur ^ 1, kt + 1);
    bf16x8 af[4], bfr[4];
#pragma unroll
    for (int ms = 0; ms < 4; ++ms)
      af[ms] = __builtin_bit_cast(bf16x8,
          *(const ushort8*)&Ab[cur][(wy * 64 + ms * 16 + ln) * 32 + g * 8]);
#pragma unroll
    for (int ns = 0; ns < 4; ++ns)
      bfr[ns] = __builtin_bit_cast(bf16x8,
          *(const ushort8*)&Bb[cur][(wx * 64 + ns * 16 + ln) * 32 + g * 8]);
#pragma unroll
    for (int ms = 0; ms < 4; ++ms)
#pragma unroll
      for (int ns = 0; ns < 4; ++ns)
        acc[ms][ns] = __builtin_amdgcn_mfma_f32_16x16x32_bf16(
            af[ms], bfr[ns], acc[ms][ns], 0, 0, 0);
  }

  float bv[4];
#pragma unroll
  for (int ns = 0; ns < 4; ++ns) bv[ns] = bias[nbase + wx * 64 + ns * 16 + ln];

  if (OUT_MODE == 0) {
    unsigned short* out = (unsigned short*)outp;
#pragma unroll
    for (int ms = 0; ms < 4; ++ms)
#pragma unroll
      for (int ns = 0; ns < 4; ++ns) {
        int col = nbase + wx * 64 + ns * 16 + ln;
#pragma unroll
        for (int j = 0; j < 4; ++j) {
          int row = mbase + wy * 64 + ms * 16 + g * 4 + j;
          out[(size_t)row * EMBED + col] = f2bf(acc[ms][ns][j] + bv[ns]);
        }
      }
  } else if (OUT_MODE == 1) {
    unsigned short* out = (unsigned short*)outp;
#pragma unroll
    for (int ms = 0; ms < 4; ++ms)
#pragma unroll
      for (int ns = 0; ns < 4; ++ns) {
        int row0 = mbase + wy * 64 + ms * 16 + g * 4;
        int col = nbase + wx * 64 + ns * 16 + ln;
        int b = row0 >> 11, s0 = row0 & (SEQ - 1);
        int h = col >> 6, d = col & 63;
        ushort4v pk;
#pragma unroll
        for (int j = 0; j < 4; ++j) pk[j] = f2bf(acc[ms][ns][j] + bv[ns]);
        *(ushort4v*)&out[(size_t)((b * HEADS + h) * HDIM + d) * SEQ + s0] = pk;
      }
  } else {
    float* out = (float*)outp;
#pragma unroll
    for (int ms = 0; ms < 4; ++ms)
#pragma unroll
      for (int ns = 0; ns < 4; ++ns) {
        int col = nbase + wx * 64 + ns * 16 + ln;
#pragma unroll
        for (int j = 0; j < 4; ++j) {
          int row = mbase + wy * 64 + ms * 16 + g * 4 + j;
          out[(size_t)row * EMBED + col] = acc[ms][ns][j] + bv[ns];
        }
      }
  }
}

// ---- attention v3: 8 waves x 32 q-rows = 256 q/block; ones-MFMA denom ----
__global__ __launch_bounds__(512, 4) void attn3_kernel(
    const unsigned short* __restrict__ qp, const unsigned short* __restrict__ kp,
    const unsigned short* __restrict__ vpT,
    const unsigned long long* __restrict__ mask64,
    unsigned short* __restrict__ attb) {
  __shared__ unsigned char lds[65536];
  unsigned char* Kb = lds;               // [2][64 rows][128B] swizzled
  unsigned char* Vb = lds + 16384;       // [2][64 rows][128B] swizzled
  unsigned char* Pb = lds + 32768;       // [8 waves][32 rows][128B]

  const int tid = threadIdx.x;
  const int lane = tid & 63, wv = tid >> 6;
  const int lo = lane & 31, hi = lane >> 5;

  // XCD-aware decode: all 8 q-chunks of one (b,h) land on one XCD
  const int flat = blockIdx.x + 8 * blockIdx.y + 128 * blockIdx.z;   // 0..511
  const int bh = (flat & 7) * 8 + ((flat >> 3) & 7);
  const int qc = flat >> 6;
  const int b = bh >> 4, h = bh & 15;
  const int qb = qc * 256 + wv * 32;
  const int q = qb + lo;

  // ---- Q fragments, pre-scaled by SCL (so p = exp2(e) directly) ----
  bf16x8 qf[4];
  {
    const unsigned short* qr = qp + (size_t)(b * SEQ + q) * EMBED + h * HDIM + hi * 8;
#pragma unroll
    for (int c = 0; c < 4; ++c) {
      ushort8 u = *(const ushort8*)(qr + 16 * c);
      bf16x8 f;
#pragma unroll
      for (int j = 0; j < 8; ++j) {
        float x = __builtin_bit_cast(float, (unsigned)u[j] << 16) * SCL;
        f[j] = (__bf16)x;
      }
      qf[c] = f;
    }
  }

  // ---- staging: 512 threads x 16B = one 8KB tile per buffer ----
  const int srow = tid >> 3;                        // 0..63
  const int srcc = ((tid & 7) * 16) ^ (((tid >> 3) & 7) << 4);  // inv swizzle
  const char* kbase = (const char*)kp
      + ((size_t)(b * SEQ + srow) * EMBED + h * HDIM) * 2 + srcc;
  const char* vbase = (const char*)vpT
      + ((size_t)((b * HEADS + h) * HDIM + srow)) * SEQ * 2 + srcc;

  auto STAGE = [&](int buf, int kt) {
    GLD_LDS16(kbase + (size_t)kt * 64 * EMBED * 2, Kb + buf * 8192 + tid * 16);
    GLD_LDS16(vbase + (size_t)kt * 128, Vb + buf * 8192 + tid * 16);
  };

  f32x16 oacc0, oacc1, oacc2;
#pragma unroll
  for (int i = 0; i < 16; ++i) { oacc0[i] = 0.f; oacc1[i] = 0.f; oacc2[i] = 0.f; }
  bf16x8 ones;
#pragma unroll
  for (int j = 0; j < 8; ++j) ones[j] = (__bf16)1.0f;

  const unsigned long long* mrow = mask64 + (size_t)(b * SEQ + q) * (SEQ / 64);
  unsigned char* Pw = Pb + wv * 4096;
  const int pswz = (lo & 7) << 4;

  STAGE(0, 0);
  const int NT = SEQ / 64;
  for (int kt = 0; kt < NT; ++kt) {
    const int cur = kt & 1;
    __syncthreads();                       // drains vmcnt; tile cur ready
    if (kt + 1 < NT) STAGE(cur ^ 1, kt + 1);
    const unsigned long long mw = mrow[kt];
    const unsigned char* Kc = Kb + cur * 8192;
    const unsigned char* Vc = Vb + cur * 8192;

    // ---- QK^T (swapped: A=K rows, B=Q rows -> D[k][q], col=lane&31=q) ----
#pragma unroll
    for (int kg = 0; kg < 2; ++kg) {
      f32x16 e;
#pragma unroll
      for (int i = 0; i < 16; ++i) e[i] = 0.f;
      const int krow = kg * 32 + lo;
#pragma unroll
      for (int c = 0; c < 4; ++c) {
        const int colb = (16 * c + 8 * hi) * 2;
        bf16x8 kf = *(const bf16x8*)(Kc + krow * 128 + (colb ^ pswz));
        e = __builtin_amdgcn_mfma_f32_32x32x16_bf16(kf, qf[c], e, 0, 0, 0);
      }
      // mask + exp + P write (k_local = kg*32 + 8t + 4hi + j)
      const unsigned mbits = (unsigned)(mw >> (kg * 32 + 4 * hi));
#pragma unroll
      for (int t = 0; t < 4; ++t) {
        ushort4v pk;
#pragma unroll
        for (int j = 0; j < 4; ++j) {
          float p = ((mbits >> (8 * t + j)) & 1u) ? exp2f(e[4 * t + j]) : 0.f;
          pk[j] = __builtin_bit_cast(unsigned short, (__bf16)p);
        }
        const int pcol = kg * 64 + 16 * t + 8 * hi;
        *(ushort4v*)(Pw + lo * 128 + (pcol ^ pswz)) = pk;
      }
    }

    // ---- PV: A=P rows (q), B=V^T rows (d) -> D[q][d]; +ones-row denom ----
#pragma unroll
    for (int c = 0; c < 4; ++c) {
      const int pcolb = 32 * c + 16 * hi;
      bf16x8 pf = *(const bf16x8*)(Pw + lo * 128 + (pcolb ^ pswz));
      {
        bf16x8 vf = *(const bf16x8*)(Vc + lo * 128 + (pcolb ^ ((lo & 7) << 4)));
        oacc0 = __builtin_amdgcn_mfma_f32_32x32x16_bf16(pf, vf, oacc0, 0, 0, 0);
      }
      {
        const int drow = 32 + lo;
        bf16x8 vf = *(const bf16x8*)(Vc + drow * 128 + (pcolb ^ ((drow & 7) << 4)));
        oacc1 = __builtin_amdgcn_mfma_f32_32x32x16_bf16(pf, vf, oacc1, 0, 0, 0);
      }
      oacc2 = __builtin_amdgcn_mfma_f32_32x32x16_bf16(pf, ones, oacc2, 0, 0, 0);
    }
  }

  // ---- oacc2[r] = sum_k P[q_r][k] (same lane layout as oacc0) ----
#pragma unroll
  for (int r = 0; r < 16; ++r) {
    const int qq = qb + (r & 3) + 8 * (r >> 2) + 4 * hi;
    const float dinv = 1.0f / oacc2[r];
    unsigned short* orow = attb + (size_t)(b * SEQ + qq) * EMBED + h * HDIM;
    orow[lo] = f2bf(oacc0[r] * dinv);
    orow[32 + lo] = f2bf(oacc1[r] * dinv);
  }
}

extern "C" void kernel_launch(void* const* d_in, const int* in_sizes, int n_in,
                              void* d_out, int out_size, void* d_ws, size_t ws_size,
                              hipStream_t stream) {
  const float* q    = (const float*)d_in[0];
  const float* k    = (const float*)d_in[1];
  const float* v    = (const float*)d_in[2];
  const int*   mask = (const int*)d_in[3];
  const float* wq_w = (const float*)d_in[4];
  const float* wq_b = (const float*)d_in[5];
  const float* wk_w = (const float*)d_in[6];
  const float* wk_b = (const float*)d_in[7];
  const float* wv_w = (const float*)d_in[8];
  const float* wv_b = (const float*)d_in[9];
  const float* fo_w = (const float*)d_in[10];
  const float* fo_b = (const float*)d_in[11];

  char* ws = (char*)d_ws;
  const size_t MB = 1024 * 1024;
  unsigned short* stage = (unsigned short*)(ws);            // 16 MB (X bf16 / attn out)
  unsigned short* wqb   = (unsigned short*)(ws + 16 * MB);  // 2 MB each
  unsigned short* wkb   = (unsigned short*)(ws + 18 * MB);
  unsigned short* wvb   = (unsigned short*)(ws + 20 * MB);
  unsigned short* fob   = (unsigned short*)(ws + 22 * MB);
  unsigned short* qp    = (unsigned short*)(ws + 24 * MB);  // 16 MB
  unsigned short* kp    = (unsigned short*)(ws + 40 * MB);  // 16 MB
  unsigned short* vpT   = (unsigned short*)(ws + 56 * MB);  // 16 MB
  unsigned long long* m64 = (unsigned long long*)(ws + 72 * MB);  // 2 MB

  const int NVX = BATCH * SEQ * EMBED / 8;   // 1048576 vec8
  const int NVW = EMBED * EMBED / 8;         // 131072 vec8

  // 1. pack mask bits (67MB -> 2MB, L3-resident for all 16 heads)
  pack_mask_kernel<<<(BATCH * SEQ * SEQ) / 256, 256, 0, stream>>>(mask, m64);

  // 2. weights -> bf16
  cvt_kernel<<<NVW / 256, 256, 0, stream>>>(wq_w, wqb, NVW);
  cvt_kernel<<<NVW / 256, 256, 0, stream>>>(wk_w, wkb, NVW);
  cvt_kernel<<<NVW / 256, 256, 0, stream>>>(wv_w, wvb, NVW);
  cvt_kernel<<<NVW / 256, 256, 0, stream>>>(fo_w, fob, NVW);

  // 3-5. projections (X staged through `stage` as bf16)
  dim3 gg((BATCH * SEQ) / 128, EMBED / 128);
  cvt_kernel<<<NVX / 256, 256, 0, stream>>>(q, stage, NVX);
  gemm_bt<0><<<gg, 256, 0, stream>>>(stage, wqb, wq_b, qp);
  cvt_kernel<<<NVX / 256, 256, 0, stream>>>(k, stage, NVX);
  gemm_bt<0><<<gg, 256, 0, stream>>>(stage, wkb, wk_b, kp);
  cvt_kernel<<<NVX / 256, 256, 0, stream>>>(v, stage, NVX);
  gemm_bt<1><<<gg, 256, 0, stream>>>(stage, wvb, wv_b, vpT);

  // 6. fused masked attention -> bf16 into `stage`
  attn3_kernel<<<dim3(8, HEADS, BATCH), 512, 0, stream>>>(qp, kp, vpT, m64, stage);

  // 7. output projection -> d_out (f32)
  gemm_bt<2><<<gg, 256, 0, stream>>>(stage, fob, fo_b, (float*)d_out);
}

// Round 4
// 285.638 us; speedup vs baseline: 2.6155x; 1.1211x over previous
//
#include <hip/hip_runtime.h>

typedef __attribute__((ext_vector_type(4))) float f32x4;
typedef __attribute__((ext_vector_type(16))) float f32x16;
typedef __attribute__((ext_vector_type(8))) __bf16 bf16x8;
typedef __attribute__((ext_vector_type(8))) unsigned short ushort8;
typedef __attribute__((ext_vector_type(4))) unsigned short ushort4v;
typedef __attribute__((ext_vector_type(4))) unsigned uint4v;

#define EMBED 1024
#define SEQ   2048
#define BATCH 4
#define HEADS 16
#define HDIM  64
// log2(e) / sqrt(EMBED) : combines the 1/32 scale with exp->exp2
#define SCL 0.045084220027780106f

#define GLD_LDS16(g, l) __builtin_amdgcn_global_load_lds( \
    (const __attribute__((address_space(1))) void*)(g),   \
    (__attribute__((address_space(3))) void*)(l), 16, 0, 0)

static __device__ __forceinline__ unsigned short f2bf(float f) {
  unsigned u = __builtin_bit_cast(unsigned, f);
  u += 0x7FFFu + ((u >> 16) & 1u);   // RNE
  return (unsigned short)(u >> 16);
}
// packed f32x2 -> bf16x2 (no builtin on gfx950; inline asm per guide m240)
static __device__ __forceinline__ unsigned cvtpk(float a, float b) {
  unsigned r;
  asm("v_cvt_pk_bf16_f32 %0, %1, %2" : "=v"(r) : "v"(a), "v"(b));
  return r;
}

// ---- pack int32 mask -> bitmask (bit k of word w = mask[w*64+k] != 0) ----
__global__ __launch_bounds__(256) void pack_mask_kernel(
    const int* __restrict__ m, unsigned long long* __restrict__ out) {
  int t = blockIdx.x * 256 + threadIdx.x;
  unsigned long long bits = __ballot(m[t] != 0);
  if ((threadIdx.x & 63) == 0) out[t >> 6] = bits;
}

// ---- f32 -> bf16 vectorized convert (8 elems/thread) ----
__global__ __launch_bounds__(256) void cvt_kernel(
    const float* __restrict__ s, unsigned short* __restrict__ d, int nvec) {
  int i = blockIdx.x * 256 + threadIdx.x;
  if (i >= nvec) return;
  f32x4 a = ((const f32x4*)s)[2 * i];
  f32x4 b = ((const f32x4*)s)[2 * i + 1];
  ushort8 o;
#pragma unroll
  for (int j = 0; j < 4; ++j) { o[j] = f2bf(a[j]); o[4 + j] = f2bf(b[j]); }
  ((ushort8*)d)[i] = o;
}

// ---- C[M x 1024] = A[M x 1024](bf16) @ B[1024 x 1024](bf16)^T + bias ----
// m97 structure: 128x128 tile, BK=32, global_load_lds w16, 1 barrier/K-step.
// OUT_MODE 0: bf16 row-major   1: bf16 vpT[b][h][d][s]   2: f32 row-major
template<int OUT_MODE>
__global__ __launch_bounds__(256) void gemm_bt(
    const unsigned short* __restrict__ A, const unsigned short* __restrict__ B,
    const float* __restrict__ bias, void* __restrict__ outp) {
  __shared__ unsigned short Ab[2][128 * 32];
  __shared__ unsigned short Bb[2][128 * 32];
  const int tid = threadIdx.x, lane = tid & 63, wv = tid >> 6;
  const int wy = wv >> 1, wx = wv & 1, ln = lane & 15, g = lane >> 4;
  const int mbase = blockIdx.x * 128, nbase = blockIdx.y * 128;

  const int srow = tid >> 2, scol = (tid & 3) * 16;
  const char* Ag = (const char*)(A + (size_t)(mbase + srow) * EMBED) + scol;
  const char* Bg = (const char*)(B + (size_t)(nbase + srow) * EMBED) + scol;
  const size_t R64 = (size_t)64 * EMBED * 2;   // 64 rows in bytes

  f32x4 acc[4][4];
#pragma unroll
  for (int i = 0; i < 4; i++)
#pragma unroll
    for (int j = 0; j < 4; j++) acc[i][j] = (f32x4){0.f, 0.f, 0.f, 0.f};

  auto STAGE = [&](int buf, int kt) {
    const size_t koff = (size_t)kt * 64;   // BK=32 bf16 = 64 bytes
    char* al = (char*)&Ab[buf][0] + tid * 16;
    char* bl = (char*)&Bb[buf][0] + tid * 16;
    GLD_LDS16(Ag + koff, al);
    GLD_LDS16(Ag + koff + R64, al + 4096);
    GLD_LDS16(Bg + koff, bl);
    GLD_LDS16(Bg + koff + R64, bl + 4096);
  };

  STAGE(0, 0);
  const int NT = EMBED / 32;
  for (int kt = 0; kt < NT; ++kt) {
    __syncthreads();                    // waves drain vmcnt -> buf kt&1 ready
    const int cur = kt & 1;
    if (kt + 1 < NT) STAGE(cur ^ 1, kt + 1);
    bf16x8 af[4], bfr[4];
#pragma unroll
    for (int ms = 0; ms < 4; ++ms)
      af[ms] = __builtin_bit_cast(bf16x8,
          *(const ushort8*)&Ab[cur][(wy * 64 + ms * 16 + ln) * 32 + g * 8]);
#pragma unroll
    for (int ns = 0; ns < 4; ++ns)
      bfr[ns] = __builtin_bit_cast(bf16x8,
          *(const ushort8*)&Bb[cur][(wx * 64 + ns * 16 + ln) * 32 + g * 8]);
#pragma unroll
    for (int ms = 0; ms < 4; ++ms)
#pragma unroll
      for (int ns = 0; ns < 4; ++ns)
        acc[ms][ns] = __builtin_amdgcn_mfma_f32_16x16x32_bf16(
            af[ms], bfr[ns], acc[ms][ns], 0, 0, 0);
  }

  float bv[4];
#pragma unroll
  for (int ns = 0; ns < 4; ++ns) bv[ns] = bias[nbase + wx * 64 + ns * 16 + ln];

  if (OUT_MODE == 0) {
    unsigned short* out = (unsigned short*)outp;
#pragma unroll
    for (int ms = 0; ms < 4; ++ms)
#pragma unroll
      for (int ns = 0; ns < 4; ++ns) {
        int col = nbase + wx * 64 + ns * 16 + ln;
#pragma unroll
        for (int j = 0; j < 4; ++j) {
          int row = mbase + wy * 64 + ms * 16 + g * 4 + j;
          out[(size_t)row * EMBED + col] = f2bf(acc[ms][ns][j] + bv[ns]);
        }
      }
  } else if (OUT_MODE == 1) {
    unsigned short* out = (unsigned short*)outp;
#pragma unroll
    for (int ms = 0; ms < 4; ++ms)
#pragma unroll
      for (int ns = 0; ns < 4; ++ns) {
        int row0 = mbase + wy * 64 + ms * 16 + g * 4;
        int col = nbase + wx * 64 + ns * 16 + ln;
        int b = row0 >> 11, s0 = row0 & (SEQ - 1);
        int h = col >> 6, d = col & 63;
        ushort4v pk;
#pragma unroll
        for (int j = 0; j < 4; ++j) pk[j] = f2bf(acc[ms][ns][j] + bv[ns]);
        *(ushort4v*)&out[(size_t)((b * HEADS + h) * HDIM + d) * SEQ + s0] = pk;
      }
  } else {
    float* out = (float*)outp;
#pragma unroll
    for (int ms = 0; ms < 4; ++ms)
#pragma unroll
      for (int ns = 0; ns < 4; ++ns) {
        int col = nbase + wx * 64 + ns * 16 + ln;
#pragma unroll
        for (int j = 0; j < 4; ++j) {
          int row = mbase + wy * 64 + ms * 16 + g * 4 + j;
          out[(size_t)row * EMBED + col] = acc[ms][ns][j] + bv[ns];
        }
      }
  }
}

// ---- attention v4: 8 waves x 32 q-rows; P fully in-register (T12) ----
__global__ __launch_bounds__(512, 4) void attn4_kernel(
    const unsigned short* __restrict__ qp, const unsigned short* __restrict__ kp,
    const unsigned short* __restrict__ vpT,
    const unsigned long long* __restrict__ mask64,
    unsigned short* __restrict__ attb) {
  __shared__ unsigned char lds[32768];
  unsigned char* Kb = lds;               // [2][64 rows][128B] swizzled
  unsigned char* Vb = lds + 16384;       // [2][64 rows][128B] swizzled

  const int tid = threadIdx.x;
  const int lane = tid & 63;
  const int lo = lane & 31, hi = lane >> 5;

  // XCD-aware decode: all 8 q-chunks of one (b,h) land on one XCD
  const int flat = blockIdx.x + 8 * blockIdx.y + 128 * blockIdx.z;   // 0..511
  const int bh = (flat & 7) * 8 + ((flat >> 3) & 7);
  const int qc = flat >> 6;
  const int b = bh >> 4, h = bh & 15;
  const int qb = qc * 256 + (tid >> 6) * 32;
  const int q = qb + lo;

  // ---- Q fragments, pre-scaled by SCL (so p = exp2(e) directly) ----
  bf16x8 qf[4];
  {
    const unsigned short* qr = qp + (size_t)(b * SEQ + q) * EMBED + h * HDIM + hi * 8;
#pragma unroll
    for (int c = 0; c < 4; ++c) {
      ushort8 u = *(const ushort8*)(qr + 16 * c);
      bf16x8 f;
#pragma unroll
      for (int j = 0; j < 8; ++j) {
        float x = __builtin_bit_cast(float, (unsigned)u[j] << 16) * SCL;
        f[j] = (__bf16)x;
      }
      qf[c] = f;
    }
  }

  // ---- staging: 512 threads x 16B = one 8KB tile per buffer ----
  const int srow = tid >> 3;                        // 0..63
  const int srcc = ((tid & 7) * 16) ^ (((tid >> 3) & 7) << 4);  // inv swizzle
  const char* kbase = (const char*)kp
      + ((size_t)(b * SEQ + srow) * EMBED + h * HDIM) * 2 + srcc;
  const char* vbase = (const char*)vpT
      + ((size_t)((b * HEADS + h) * HDIM + srow)) * SEQ * 2 + srcc;

  auto STAGE = [&](int buf, int kt) {
    GLD_LDS16(kbase + (size_t)kt * 64 * EMBED * 2, Kb + buf * 8192 + tid * 16);
    GLD_LDS16(vbase + (size_t)kt * 128, Vb + buf * 8192 + tid * 16);
  };

  f32x16 oacc0, oacc1, oacc2;
#pragma unroll
  for (int i = 0; i < 16; ++i) { oacc0[i] = 0.f; oacc1[i] = 0.f; oacc2[i] = 0.f; }
  bf16x8 ones;
#pragma unroll
  for (int j = 0; j < 8; ++j) ones[j] = (__bf16)1.0f;

  const unsigned long long* mrow = mask64 + (size_t)(b * SEQ + q) * (SEQ / 64);
  const int swz = (lo & 7) << 4;

  STAGE(0, 0);
  const int NT = SEQ / 64;
  for (int kt = 0; kt < NT; ++kt) {
    const int cur = kt & 1;
    __syncthreads();                       // drains vmcnt; tile cur ready
    if (kt + 1 < NT) STAGE(cur ^ 1, kt + 1);
    const unsigned long long mw = mrow[kt];
    const unsigned char* Kc = Kb + cur * 8192;
    const unsigned char* Vc = Vb + cur * 8192;

    // ---- QK^T (swapped: A=K, B=Q -> D[k][q]) + in-register P build ----
    bf16x8 PA[4];
#pragma unroll
    for (int kg = 0; kg < 2; ++kg) {
      f32x16 e;
#pragma unroll
      for (int i = 0; i < 16; ++i) e[i] = 0.f;
      const int krow = kg * 32 + lo;
#pragma unroll
      for (int c = 0; c < 4; ++c) {
        const int colb = (16 * c + 8 * hi) * 2;
        bf16x8 kf = *(const bf16x8*)(Kc + krow * 128 + (colb ^ swz));
        e = __builtin_amdgcn_mfma_f32_32x32x16_bf16(kf, qf[c], e, 0, 0, 0);
      }
      // mask + exp: p[4m+j] is k_local = 8m + 4hi + j; bit (8m+j) of mh
      const unsigned mh = (unsigned)(mw >> (kg * 32 + 4 * hi));
      float p[16];
#pragma unroll
      for (int m = 0; m < 4; ++m)
#pragma unroll
        for (int j = 0; j < 4; ++j) {
          float pe = __builtin_amdgcn_exp2f(e[4 * m + j]);
          p[4 * m + j] = (mh & (1u << (8 * m + j))) ? pe : 0.f;
        }
      // pack pairs to bf16; swap lane-halves: one permlane fills 2 words
      unsigned wA0 = cvtpk(p[0], p[1]),   wB0 = cvtpk(p[2], p[3]);
      unsigned wA1 = cvtpk(p[4], p[5]),   wB1 = cvtpk(p[6], p[7]);
      unsigned wA2 = cvtpk(p[8], p[9]),   wB2 = cvtpk(p[10], p[11]);
      unsigned wA3 = cvtpk(p[12], p[13]), wB3 = cvtpk(p[14], p[15]);
      asm("v_permlane32_swap_b32 %0, %1" : "+v"(wA0), "+v"(wA1));
      asm("v_permlane32_swap_b32 %0, %1" : "+v"(wB0), "+v"(wB1));
      asm("v_permlane32_swap_b32 %0, %1" : "+v"(wA2), "+v"(wA3));
      asm("v_permlane32_swap_b32 %0, %1" : "+v"(wB2), "+v"(wB3));
      PA[2 * kg]     = __builtin_bit_cast(bf16x8, (uint4v){wA0, wB0, wA1, wB1});
      PA[2 * kg + 1] = __builtin_bit_cast(bf16x8, (uint4v){wA2, wB2, wA3, wB3});
    }

    // ---- PV: A=P (in reg), B=V^T rows (d) -> D[q][d]; +ones denom ----
    __builtin_amdgcn_s_setprio(1);
#pragma unroll
    for (int c = 0; c < 4; ++c) {
      const int pcolb = 32 * c + 16 * hi;
      bf16x8 pf = PA[c];
      {
        bf16x8 vf = *(const bf16x8*)(Vc + lo * 128 + (pcolb ^ swz));
        oacc0 = __builtin_amdgcn_mfma_f32_32x32x16_bf16(pf, vf, oacc0, 0, 0, 0);
      }
      {
        const int drow = 32 + lo;
        bf16x8 vf = *(const bf16x8*)(Vc + drow * 128 + (pcolb ^ swz));
        oacc1 = __builtin_amdgcn_mfma_f32_32x32x16_bf16(pf, vf, oacc1, 0, 0, 0);
      }
      oacc2 = __builtin_amdgcn_mfma_f32_32x32x16_bf16(pf, ones, oacc2, 0, 0, 0);
    }
    __builtin_amdgcn_s_setprio(0);
  }

  // ---- oacc2[r] = sum_k P[q_r][k] (same lane layout as oacc0) ----
#pragma unroll
  for (int r = 0; r < 16; ++r) {
    const int qq = qb + (r & 3) + 8 * (r >> 2) + 4 * hi;
    const float dinv = 1.0f / oacc2[r];
    unsigned short* orow = attb + (size_t)(b * SEQ + qq) * EMBED + h * HDIM;
    orow[lo] = f2bf(oacc0[r] * dinv);
    orow[32 + lo] = f2bf(oacc1[r] * dinv);
  }
}

extern "C" void kernel_launch(void* const* d_in, const int* in_sizes, int n_in,
                              void* d_out, int out_size, void* d_ws, size_t ws_size,
                              hipStream_t stream) {
  const float* q    = (const float*)d_in[0];
  const float* k    = (const float*)d_in[1];
  const float* v    = (const float*)d_in[2];
  const int*   mask = (const int*)d_in[3];
  const float* wq_w = (const float*)d_in[4];
  const float* wq_b = (const float*)d_in[5];
  const float* wk_w = (const float*)d_in[6];
  const float* wk_b = (const float*)d_in[7];
  const float* wv_w = (const float*)d_in[8];
  const float* wv_b = (const float*)d_in[9];
  const float* fo_w = (const float*)d_in[10];
  const float* fo_b = (const float*)d_in[11];

  char* ws = (char*)d_ws;
  const size_t MB = 1024 * 1024;
  unsigned short* stage = (unsigned short*)(ws);            // 16 MB (X bf16 / attn out)
  unsigned short* wqb   = (unsigned short*)(ws + 16 * MB);  // 2 MB each
  unsigned short* wkb   = (unsigned short*)(ws + 18 * MB);
  unsigned short* wvb   = (unsigned short*)(ws + 20 * MB);
  unsigned short* fob   = (unsigned short*)(ws + 22 * MB);
  unsigned short* qp    = (unsigned short*)(ws + 24 * MB);  // 16 MB
  unsigned short* kp    = (unsigned short*)(ws + 40 * MB);  // 16 MB
  unsigned short* vpT   = (unsigned short*)(ws + 56 * MB);  // 16 MB
  unsigned long long* m64 = (unsigned long long*)(ws + 72 * MB);  // 2 MB

  const int NVX = BATCH * SEQ * EMBED / 8;   // 1048576 vec8
  const int NVW = EMBED * EMBED / 8;         // 131072 vec8

  // 1. pack mask bits (67MB -> 2MB, L3-resident for all 16 heads)
  pack_mask_kernel<<<(BATCH * SEQ * SEQ) / 256, 256, 0, stream>>>(mask, m64);

  // 2. weights -> bf16
  cvt_kernel<<<NVW / 256, 256, 0, stream>>>(wq_w, wqb, NVW);
  cvt_kernel<<<NVW / 256, 256, 0, stream>>>(wk_w, wkb, NVW);
  cvt_kernel<<<NVW / 256, 256, 0, stream>>>(wv_w, wvb, NVW);
  cvt_kernel<<<NVW / 256, 256, 0, stream>>>(fo_w, fob, NVW);

  // 3-5. projections (X staged through `stage` as bf16)
  dim3 gg((BATCH * SEQ) / 128, EMBED / 128);
  cvt_kernel<<<NVX / 256, 256, 0, stream>>>(q, stage, NVX);
  gemm_bt<0><<<gg, 256, 0, stream>>>(stage, wqb, wq_b, qp);
  cvt_kernel<<<NVX / 256, 256, 0, stream>>>(k, stage, NVX);
  gemm_bt<0><<<gg, 256, 0, stream>>>(stage, wkb, wk_b, kp);
  cvt_kernel<<<NVX / 256, 256, 0, stream>>>(v, stage, NVX);
  gemm_bt<1><<<gg, 256, 0, stream>>>(stage, wvb, wv_b, vpT);

  // 6. fused masked attention -> bf16 into `stage`
  attn4_kernel<<<dim3(8, HEADS, BATCH), 512, 0, stream>>>(qp, kp, vpT, m64, stage);

  // 7. output projection -> d_out (f32)
  gemm_bt<2><<<gg, 256, 0, stream>>>(stage, fob, fo_b, (float*)d_out);
}

// Round 5
// 260.847 us; speedup vs baseline: 2.8641x; 1.0950x over previous
//
#include <hip/hip_runtime.h>

typedef __attribute__((ext_vector_type(4))) float f32x4;
typedef __attribute__((ext_vector_type(16))) float f32x16;
typedef __attribute__((ext_vector_type(8))) __bf16 bf16x8;
typedef __attribute__((ext_vector_type(8))) unsigned short ushort8;
typedef __attribute__((ext_vector_type(4))) unsigned short ushort4v;
typedef __attribute__((ext_vector_type(4))) unsigned uint4v;

#define EMBED 1024
#define SEQ   2048
#define BATCH 4
#define HEADS 16
#define HDIM  64
// log2(e) / sqrt(EMBED) : combines the 1/32 scale with exp->exp2
#define SCL 0.045084220027780106f

#define GLD_LDS16(g, l) __builtin_amdgcn_global_load_lds( \
    (const __attribute__((address_space(1))) void*)(g),   \
    (__attribute__((address_space(3))) void*)(l), 16, 0, 0)
#define GLD_LDS4(g, l) __builtin_amdgcn_global_load_lds(  \
    (const __attribute__((address_space(1))) void*)(g),   \
    (__attribute__((address_space(3))) void*)(l), 4, 0, 0)

static __device__ __forceinline__ unsigned short f2bf(float f) {
  unsigned u = __builtin_bit_cast(unsigned, f);
  u += 0x7FFFu + ((u >> 16) & 1u);   // RNE
  return (unsigned short)(u >> 16);
}
// packed f32x2 -> bf16x2 (no builtin on gfx950; inline asm per guide m240)
static __device__ __forceinline__ unsigned cvtpk(float a, float b) {
  unsigned r;
  asm("v_cvt_pk_bf16_f32 %0, %1, %2" : "=v"(r) : "v"(a), "v"(b));
  return r;
}

// ---- pack int32 mask -> bitmask (bit k of word w = mask[w*64+k] != 0) ----
__global__ __launch_bounds__(256) void pack_mask_kernel(
    const int* __restrict__ m, unsigned long long* __restrict__ out) {
  int t = blockIdx.x * 256 + threadIdx.x;
  unsigned long long bits = __ballot(m[t] != 0);
  if ((threadIdx.x & 63) == 0) out[t >> 6] = bits;
}

// ---- f32 -> bf16 vectorized convert (8 elems/thread) ----
__global__ __launch_bounds__(256) void cvt_kernel(
    const float* __restrict__ s, unsigned short* __restrict__ d, int nvec) {
  int i = blockIdx.x * 256 + threadIdx.x;
  if (i >= nvec) return;
  f32x4 a = ((const f32x4*)s)[2 * i];
  f32x4 b = ((const f32x4*)s)[2 * i + 1];
  ushort8 o;
#pragma unroll
  for (int j = 0; j < 4; ++j) { o[j] = f2bf(a[j]); o[4 + j] = f2bf(b[j]); }
  ((ushort8*)d)[i] = o;
}

// ---- 4 weight matrices -> bf16 in one launch (dsts contiguous) ----
__global__ __launch_bounds__(256) void cvt4_kernel(
    const float* __restrict__ s0, const float* __restrict__ s1,
    const float* __restrict__ s2, const float* __restrict__ s3,
    unsigned short* __restrict__ d, int nvec) {
  int i = blockIdx.x * 256 + threadIdx.x;
  if (i >= nvec) return;
  const float* s = (blockIdx.y == 0) ? s0 : (blockIdx.y == 1) ? s1
                 : (blockIdx.y == 2) ? s2 : s3;
  unsigned short* dd = d + (size_t)blockIdx.y * nvec * 8;
  f32x4 a = ((const f32x4*)s)[2 * i];
  f32x4 b = ((const f32x4*)s)[2 * i + 1];
  ushort8 o;
#pragma unroll
  for (int j = 0; j < 4; ++j) { o[j] = f2bf(a[j]); o[4 + j] = f2bf(b[j]); }
  ((ushort8*)dd)[i] = o;
}

// ---- C[M x 1024] = A[M x 1024](bf16) @ B[1024 x 1024](bf16)^T + bias ----
// 128x128 tile, BK=32, global_load_lds w16, TRIPLE buffer + counted vmcnt:
// iter t reads buf[t%3]; stages t+2 into buf[(t+2)%3] (= tile t-1's buffer,
// fully read before this iteration's barrier). vmcnt ledger: stage=4 loads;
// queue at wait = [t:4][t+1:4][t+2:4] -> vmcnt(8); tail 4/0.
template<int OUT_MODE>
__global__ __launch_bounds__(256, 3) void gemm_bt(
    const unsigned short* __restrict__ A, const unsigned short* __restrict__ B,
    const float* __restrict__ bias, void* __restrict__ outp) {
  __shared__ unsigned short Ab[3 * 128 * 32];
  __shared__ unsigned short Bb[3 * 128 * 32];
  const int tid = threadIdx.x, lane = tid & 63, wv = tid >> 6;
  const int wy = wv >> 1, wx = wv & 1, ln = lane & 15, g = lane >> 4;
  const int mbase = blockIdx.x * 128, nbase = blockIdx.y * 128;

  const int srow = tid >> 2, scol = (tid & 3) * 16;
  const char* Ag = (const char*)(A + (size_t)(mbase + srow) * EMBED) + scol;
  const char* Bg = (const char*)(B + (size_t)(nbase + srow) * EMBED) + scol;
  const size_t R64 = (size_t)64 * EMBED * 2;   // 64 rows in bytes

  f32x4 acc[4][4];
#pragma unroll
  for (int i = 0; i < 4; i++)
#pragma unroll
    for (int j = 0; j < 4; j++) acc[i][j] = (f32x4){0.f, 0.f, 0.f, 0.f};

  auto STAGE = [&](int buf, int kt) {
    const size_t koff = (size_t)kt * 64;   // BK=32 bf16 = 64 bytes
    char* al = (char*)Ab + buf * 8192 + tid * 16;
    char* bl = (char*)Bb + buf * 8192 + tid * 16;
    GLD_LDS16(Ag + koff, al);
    GLD_LDS16(Ag + koff + R64, al + 4096);
    GLD_LDS16(Bg + koff, bl);
    GLD_LDS16(Bg + koff + R64, bl + 4096);
  };

  STAGE(0, 0);
  STAGE(1, 1);
  const int NT = EMBED / 32;
  int buf = 0;
  for (int kt = 0; kt < NT; ++kt) {
    __builtin_amdgcn_s_barrier();
    if (kt + 2 < NT) {
      int nb = buf + 2; if (nb >= 3) nb -= 3;
      STAGE(nb, kt + 2);
      asm volatile("s_waitcnt vmcnt(8)" ::: "memory");
    } else if (kt + 1 < NT) {
      asm volatile("s_waitcnt vmcnt(4)" ::: "memory");
    } else {
      asm volatile("s_waitcnt vmcnt(0)" ::: "memory");
    }
    __builtin_amdgcn_sched_barrier(0);
    bf16x8 af[4], bfr[4];
#pragma unroll
    for (int ms = 0; ms < 4; ++ms)
      af[ms] = __builtin_bit_cast(bf16x8,
          *(const ushort8*)&Ab[buf * 4096 + (wy * 64 + ms * 16 + ln) * 32 + g * 8]);
#pragma unroll
    for (int ns = 0; ns < 4; ++ns)
      bfr[ns] = __builtin_bit_cast(bf16x8,
          *(const ushort8*)&Bb[buf * 4096 + (wx * 64 + ns * 16 + ln) * 32 + g * 8]);
#pragma unroll
    for (int ms = 0; ms < 4; ++ms)
#pragma unroll
      for (int ns = 0; ns < 4; ++ns)
        acc[ms][ns] = __builtin_amdgcn_mfma_f32_16x16x32_bf16(
            af[ms], bfr[ns], acc[ms][ns], 0, 0, 0);
    buf = (buf == 2) ? 0 : buf + 1;
  }

  float bv[4];
#pragma unroll
  for (int ns = 0; ns < 4; ++ns) bv[ns] = bias[nbase + wx * 64 + ns * 16 + ln];

  if (OUT_MODE == 0) {
    unsigned short* out = (unsigned short*)outp;
#pragma unroll
    for (int ms = 0; ms < 4; ++ms)
#pragma unroll
      for (int ns = 0; ns < 4; ++ns) {
        int col = nbase + wx * 64 + ns * 16 + ln;
#pragma unroll
        for (int j = 0; j < 4; ++j) {
          int row = mbase + wy * 64 + ms * 16 + g * 4 + j;
          out[(size_t)row * EMBED + col] = f2bf(acc[ms][ns][j] + bv[ns]);
        }
      }
  } else if (OUT_MODE == 1) {
    unsigned short* out = (unsigned short*)outp;
#pragma unroll
    for (int ms = 0; ms < 4; ++ms)
#pragma unroll
      for (int ns = 0; ns < 4; ++ns) {
        int row0 = mbase + wy * 64 + ms * 16 + g * 4;
        int col = nbase + wx * 64 + ns * 16 + ln;
        int b = row0 >> 11, s0 = row0 & (SEQ - 1);
        int h = col >> 6, d = col & 63;
        ushort4v pk;
#pragma unroll
        for (int j = 0; j < 4; ++j) pk[j] = f2bf(acc[ms][ns][j] + bv[ns]);
        *(ushort4v*)&out[(size_t)((b * HEADS + h) * HDIM + d) * SEQ + s0] = pk;
      }
  } else {
    float* out = (float*)outp;
#pragma unroll
    for (int ms = 0; ms < 4; ++ms)
#pragma unroll
      for (int ns = 0; ns < 4; ++ns) {
        int col = nbase + wx * 64 + ns * 16 + ln;
#pragma unroll
        for (int j = 0; j < 4; ++j) {
          int row = mbase + wy * 64 + ms * 16 + g * 4 + j;
          out[(size_t)row * EMBED + col] = acc[ms][ns][j] + bv[ns];
        }
      }
  }
}

// ---- attention v5: triple-buffered K/V/mask + counted vmcnt ----
// stage = 3 loads (K16,V16,M4): queue [t:3][t+1:3][t+2:3] -> vmcnt(6); tail 3/0.
__global__ __launch_bounds__(512, 4) void attn5_kernel(
    const unsigned short* __restrict__ qp, const unsigned short* __restrict__ kp,
    const unsigned short* __restrict__ vpT,
    const unsigned long long* __restrict__ mask64,
    unsigned short* __restrict__ attb) {
  __shared__ unsigned char lds[55296];
  unsigned char* Kb = lds;               // [3][64 rows][128B] swizzled
  unsigned char* Vb = lds + 24576;       // [3][64 rows][128B] swizzled
  unsigned char* Mb = lds + 49152;       // [3][256 rows][8B]

  const int tid = threadIdx.x;
  const int lane = tid & 63, wv = tid >> 6;
  const int lo = lane & 31, hi = lane >> 5;

  // XCD-aware decode: all 8 q-chunks of one (b,h) land on one XCD
  const int flat = blockIdx.x + 8 * blockIdx.y + 128 * blockIdx.z;   // 0..511
  const int bh = (flat & 7) * 8 + ((flat >> 3) & 7);
  const int qc = flat >> 6;
  const int b = bh >> 4, h = bh & 15;
  const int qb = qc * 256 + wv * 32;
  const int q = qb + lo;

  // ---- Q fragments, pre-scaled by SCL (so p = exp2(e) directly) ----
  bf16x8 qf[4];
  {
    const unsigned short* qr = qp + (size_t)(b * SEQ + q) * EMBED + h * HDIM + hi * 8;
#pragma unroll
    for (int c = 0; c < 4; ++c) {
      ushort8 u = *(const ushort8*)(qr + 16 * c);
      bf16x8 f;
#pragma unroll
      for (int j = 0; j < 8; ++j) {
        float x = __builtin_bit_cast(float, (unsigned)u[j] << 16) * SCL;
        f[j] = (__bf16)x;
      }
      qf[c] = f;
    }
  }

  // ---- staging: 512 threads; K,V: 16B each; mask: 4B each (256 rows x 8B) ----
  const int srow = tid >> 3;                        // 0..63
  const int srcc = ((tid & 7) * 16) ^ (((tid >> 3) & 7) << 4);  // inv swizzle
  const char* kbase = (const char*)kp
      + ((size_t)(b * SEQ + srow) * EMBED + h * HDIM) * 2 + srcc;
  const char* vbase = (const char*)vpT
      + ((size_t)((b * HEADS + h) * HDIM + srow)) * SEQ * 2 + srcc;
  const char* mgbase = (const char*)mask64
      + ((size_t)(b * SEQ + qc * 256 + (tid >> 1)) * 32) * 8 + (tid & 1) * 4;

  auto STAGE = [&](int buf, int kt) {
    GLD_LDS16(kbase + (size_t)kt * 64 * EMBED * 2, Kb + buf * 8192 + tid * 16);
    GLD_LDS16(vbase + (size_t)kt * 128, Vb + buf * 8192 + tid * 16);
    GLD_LDS4(mgbase + kt * 8, Mb + buf * 2048 + tid * 4);
  };

  f32x16 oacc0, oacc1, oacc2;
#pragma unroll
  for (int i = 0; i < 16; ++i) { oacc0[i] = 0.f; oacc1[i] = 0.f; oacc2[i] = 0.f; }
  bf16x8 ones;
#pragma unroll
  for (int j = 0; j < 8; ++j) ones[j] = (__bf16)1.0f;

  const int swz = (lo & 7) << 4;

  STAGE(0, 0);
  STAGE(1, 1);
  const int NT = SEQ / 64;
  int buf = 0;
  for (int kt = 0; kt < NT; ++kt) {
    __builtin_amdgcn_s_barrier();
    if (kt + 2 < NT) {
      int nb = buf + 2; if (nb >= 3) nb -= 3;
      STAGE(nb, kt + 2);
      asm volatile("s_waitcnt vmcnt(6)" ::: "memory");
    } else if (kt + 1 < NT) {
      asm volatile("s_waitcnt vmcnt(3)" ::: "memory");
    } else {
      asm volatile("s_waitcnt vmcnt(0)" ::: "memory");
    }
    __builtin_amdgcn_sched_barrier(0);
    const unsigned char* Kc = Kb + buf * 8192;
    const unsigned char* Vc = Vb + buf * 8192;
    const unsigned long long mw =
        *(const unsigned long long*)(Mb + buf * 2048 + (wv * 32 + lo) * 8);

    // ---- QK^T (swapped: A=K, B=Q -> D[k][q]) + in-register P build ----
    bf16x8 PA[4];
#pragma unroll
    for (int kg = 0; kg < 2; ++kg) {
      f32x16 e;
#pragma unroll
      for (int i = 0; i < 16; ++i) e[i] = 0.f;
      const int krow = kg * 32 + lo;
#pragma unroll
      for (int c = 0; c < 4; ++c) {
        const int colb = (16 * c + 8 * hi) * 2;
        bf16x8 kf = *(const bf16x8*)(Kc + krow * 128 + (colb ^ swz));
        e = __builtin_amdgcn_mfma_f32_32x32x16_bf16(kf, qf[c], e, 0, 0, 0);
      }
      // mask + exp: p[4m+j] is k_local = 8m + 4hi + j; bit (8m+j) of mh
      const unsigned mh = (unsigned)(mw >> (kg * 32 + 4 * hi));
      float p[16];
#pragma unroll
      for (int m = 0; m < 4; ++m)
#pragma unroll
        for (int j = 0; j < 4; ++j) {
          float pe = __builtin_amdgcn_exp2f(e[4 * m + j]);
          p[4 * m + j] = (mh & (1u << (8 * m + j))) ? pe : 0.f;
        }
      // pack pairs to bf16; swap lane-halves: one permlane fills 2 words
      unsigned wA0 = cvtpk(p[0], p[1]),   wB0 = cvtpk(p[2], p[3]);
      unsigned wA1 = cvtpk(p[4], p[5]),   wB1 = cvtpk(p[6], p[7]);
      unsigned wA2 = cvtpk(p[8], p[9]),   wB2 = cvtpk(p[10], p[11]);
      unsigned wA3 = cvtpk(p[12], p[13]), wB3 = cvtpk(p[14], p[15]);
      asm("v_permlane32_swap_b32 %0, %1" : "+v"(wA0), "+v"(wA1));
      asm("v_permlane32_swap_b32 %0, %1" : "+v"(wB0), "+v"(wB1));
      asm("v_permlane32_swap_b32 %0, %1" : "+v"(wA2), "+v"(wA3));
      asm("v_permlane32_swap_b32 %0, %1" : "+v"(wB2), "+v"(wB3));
      PA[2 * kg]     = __builtin_bit_cast(bf16x8, (uint4v){wA0, wB0, wA1, wB1});
      PA[2 * kg + 1] = __builtin_bit_cast(bf16x8, (uint4v){wA2, wB2, wA3, wB3});
    }

    // ---- PV: A=P (in reg), B=V^T rows (d) -> D[q][d]; +ones denom ----
    __builtin_amdgcn_s_setprio(1);
#pragma unroll
    for (int c = 0; c < 4; ++c) {
      const int pcolb = 32 * c + 16 * hi;
      bf16x8 pf = PA[c];
      {
        bf16x8 vf = *(const bf16x8*)(Vc + lo * 128 + (pcolb ^ swz));
        oacc0 = __builtin_amdgcn_mfma_f32_32x32x16_bf16(pf, vf, oacc0, 0, 0, 0);
      }
      {
        const int drow = 32 + lo;
        bf16x8 vf = *(const bf16x8*)(Vc + drow * 128 + (pcolb ^ swz));
        oacc1 = __builtin_amdgcn_mfma_f32_32x32x16_bf16(pf, vf, oacc1, 0, 0, 0);
      }
      oacc2 = __builtin_amdgcn_mfma_f32_32x32x16_bf16(pf, ones, oacc2, 0, 0, 0);
    }
    __builtin_amdgcn_s_setprio(0);
    buf = (buf == 2) ? 0 : buf + 1;
  }

  // ---- oacc2[r] = sum_k P[q_r][k] (same lane layout as oacc0) ----
#pragma unroll
  for (int r = 0; r < 16; ++r) {
    const int qq = qb + (r & 3) + 8 * (r >> 2) + 4 * hi;
    const float dinv = 1.0f / oacc2[r];
    unsigned short* orow = attb + (size_t)(b * SEQ + qq) * EMBED + h * HDIM;
    orow[lo] = f2bf(oacc0[r] * dinv);
    orow[32 + lo] = f2bf(oacc1[r] * dinv);
  }
}

extern "C" void kernel_launch(void* const* d_in, const int* in_sizes, int n_in,
                              void* d_out, int out_size, void* d_ws, size_t ws_size,
                              hipStream_t stream) {
  const float* q    = (const float*)d_in[0];
  const float* k    = (const float*)d_in[1];
  const float* v    = (const float*)d_in[2];
  const int*   mask = (const int*)d_in[3];
  const float* wq_w = (const float*)d_in[4];
  const float* wq_b = (const float*)d_in[5];
  const float* wk_w = (const float*)d_in[6];
  const float* wk_b = (const float*)d_in[7];
  const float* wv_w = (const float*)d_in[8];
  const float* wv_b = (const float*)d_in[9];
  const float* fo_w = (const float*)d_in[10];
  const float* fo_b = (const float*)d_in[11];

  char* ws = (char*)d_ws;
  const size_t MB = 1024 * 1024;
  unsigned short* stage = (unsigned short*)(ws);            // 16 MB (X bf16 / attn out)
  unsigned short* wqb   = (unsigned short*)(ws + 16 * MB);  // 2 MB each, contiguous
  unsigned short* qp    = (unsigned short*)(ws + 24 * MB);  // 16 MB
  unsigned short* kp    = (unsigned short*)(ws + 40 * MB);  // 16 MB
  unsigned short* vpT   = (unsigned short*)(ws + 56 * MB);  // 16 MB
  unsigned long long* m64 = (unsigned long long*)(ws + 72 * MB);  // 2 MB

  const int NVX = BATCH * SEQ * EMBED / 8;   // 1048576 vec8
  const int NVW = EMBED * EMBED / 8;         // 131072 vec8

  // 1. pack mask bits (67MB -> 2MB, L3-resident for all 16 heads)
  pack_mask_kernel<<<(BATCH * SEQ * SEQ) / 256, 256, 0, stream>>>(mask, m64);

  // 2. weights -> bf16 (one launch; dsts contiguous at ws+16MB)
  cvt4_kernel<<<dim3(NVW / 256, 4), 256, 0, stream>>>(wq_w, wk_w, wv_w, fo_w, wqb, NVW);
  unsigned short* wkb = wqb + (size_t)NVW * 8;
  unsigned short* wvb = wkb + (size_t)NVW * 8;
  unsigned short* fob = wvb + (size_t)NVW * 8;

  // 3-5. projections (X staged through `stage` as bf16)
  dim3 gg((BATCH * SEQ) / 128, EMBED / 128);
  cvt_kernel<<<NVX / 256, 256, 0, stream>>>(q, stage, NVX);
  gemm_bt<0><<<gg, 256, 0, stream>>>(stage, wqb, wq_b, qp);
  cvt_kernel<<<NVX / 256, 256, 0, stream>>>(k, stage, NVX);
  gemm_bt<0><<<gg, 256, 0, stream>>>(stage, wkb, wk_b, kp);
  cvt_kernel<<<NVX / 256, 256, 0, stream>>>(v, stage, NVX);
  gemm_bt<1><<<gg, 256, 0, stream>>>(stage, wvb, wv_b, vpT);

  // 6. fused masked attention -> bf16 into `stage`
  attn5_kernel<<<dim3(8, HEADS, BATCH), 512, 0, stream>>>(qp, kp, vpT, m64, stage);

  // 7. output projection -> d_out (f32)
  gemm_bt<2><<<gg, 256, 0, stream>>>(stage, fob, fo_b, (float*)d_out);
}